// Round 24
// baseline (5354.422 us; speedup 1.0000x reference)
//
#include <hip/hip_runtime.h>
#include <hip/hip_fp16.h>

// ---------------------------------------------------------------------------
// 2-layer LSTM (B=256, T=256, D=128, H=1024) + final Linear(H->128).
// Persistent kernel, one phase per timestep. fp16 MFMA, fp32 accum.
// Weights in LDS; h/x in coalesced tiled layout (R22); ring-12 asm pipeline
// (R23).
//
// R24: CACHED h-STORES + PER-XCD RELEASE-WRITEBACK. Write-through h-stores
// were streaming past the IF to HBM (WRITE_SIZE = h flux; FETCH = 4.4MB/ph
// of HBM reads at ~300GB/s = the whole phase). Now: plain cached stores
// (dirty XCD-L2; each 128B line written wholly within one XCD) ->
// slot-0 release fence (buffer_wbl2 -> IF allocates writebacks) -> global
// handshake -> acquire inv -> readers hit IF instead of HBM.
// Protocol: arr[xcd*32+slot] -> slot-0 polls 32, RELEASE, garr[xcd] ->
// slot-0 polls 8 garr, ACQUIRE(L2+L1), xcdgo -> others poll xcdgo, L1-inv.
// ---------------------------------------------------------------------------

#define Bq 256
#define Hq 1024

typedef _Float16 half8 __attribute__((ext_vector_type(8)));
typedef float    floatx4 __attribute__((ext_vector_type(4)));

#define N_W1 8388608LL   // 128 cb * 65536  ([ks64][kb4][n2][jj16][e8])
#define N_W0 4718592LL   // 128 cb * 36864  ([ks36][kb4][n2][jj16][e8])
#define N_XH 8388608LL   // T*B*D  (tiled: [t][4][256][32])
#define N_H  262144LL    // B*H
#define BH   262144

// ws byte offsets
#define OFF_W1 0LL
#define OFF_W0 16777216LL
#define OFF_XH 26214400LL
#define OFF_BA 42991616LL
#define OFF_BB 44040192LL
#define OFF_HF 45088768LL
#define OFF_SY 46137344LL
#define REQ_WS 46139392LL   // OFF_SY + 2048

// sync layout (uints): [0..255]=arr (xcd*32+slot), [256+xcd*16]=garr,
//                      [384+xcd*16]=xcdgo
// ---------------------------------------------------------------------------
__global__ void ws_sentinel_kernel(float* __restrict__ out, int n, float v)
{
    int i = blockIdx.x * blockDim.x + threadIdx.x;
    if (i < n) out[i] = v;
}

// ---------------------------------------------------------------------------
__global__ void prep_kernel(const float* __restrict__ x, const float* __restrict__ h0,
                            const float* __restrict__ Wih0, const float* __restrict__ Whh0,
                            const float* __restrict__ Wih1, const float* __restrict__ Whh1,
                            _Float16* __restrict__ w1p, _Float16* __restrict__ w0p,
                            _Float16* __restrict__ xh,
                            _Float16* __restrict__ bufA, _Float16* __restrict__ bufB,
                            unsigned* __restrict__ sync)
{
    long long gid = (long long)blockIdx.x * blockDim.x + threadIdx.x;
    if (gid < 512) sync[gid] = 0u;

    if (gid < N_W1) {
        // [cb][ks][kb][n][jj][e]; gate-col row = (2n + jj>>3)*1024 + cb*8 + (jj&7)
        long long i = gid;
        int e  = (int)(i & 7);
        int jj = (int)((i >> 3) & 15);
        int n  = (int)((i >> 7) & 1);
        int kb = (int)((i >> 8) & 3);
        int ks = (int)((i >> 10) & 63);
        int cb = (int)(i >> 16);
        int row = (2 * n + (jj >> 3)) * 1024 + cb * 8 + (jj & 7);
        int k = ks * 32 + kb * 8 + e;
        float v = (k < 1024) ? Wih1[(size_t)row * 1024 + k]
                             : Whh1[(size_t)row * 1024 + (k - 1024)];
        w1p[i] = (_Float16)v;
    } else if (gid < N_W1 + N_W0) {
        long long i = gid - N_W1;
        int cb = (int)(i / 36864LL);
        int r  = (int)(i - (long long)cb * 36864LL);
        int ks = r >> 10;
        int kb = (r >> 8) & 3;
        int n  = (r >> 7) & 1;
        int jj = (r >> 3) & 15;
        int e  = r & 7;
        int row = (2 * n + (jj >> 3)) * 1024 + cb * 8 + (jj & 7);
        int k = ks * 32 + kb * 8 + e;
        float v = (k < 128) ? Wih0[(size_t)row * 128 + k]
                            : Whh0[(size_t)row * 1024 + (k - 128)];
        w0p[i] = (_Float16)v;
    } else if (gid < N_W1 + N_W0 + N_XH) {
        long long i = gid - N_W1 - N_W0;
        // xh tiled: [t][tile4][b][32]; element d = tile*32+e of x[b][t][:]
        int t    = (int)(i >> 15);
        int rem  = (int)(i & 32767);
        int tile = rem >> 13;
        int b    = (rem >> 5) & 255;
        int e    = rem & 31;
        int d    = tile * 32 + e;
        xh[i] = (_Float16)x[((size_t)b * 256 + t) * 128 + d];
    } else if (gid < N_W1 + N_W0 + N_XH + N_H) {
        long long i = gid - N_W1 - N_W0 - N_XH;
        // h0 is [row][H]; tiled dest idx = (j>>5)*8192 + row*32 + (j&31)
        int row = (int)(i >> 10);
        int j   = (int)(i & 1023);
        size_t idx = (size_t)(j >> 5) * 8192 + (size_t)row * 32 + (j & 31);
        _Float16 v = (_Float16)h0[i];
        bufA[BH + idx] = v;   // h_a(-1) parity 1
        bufB[BH + idx] = v;   // h_b(-1) parity 1
    }
}

// ---------------------------------------------------------------------------
// Phase barrier with per-XCD release-writeback and single L2-inv.
//  all blocks: drain stores (in local L2), publish arr[xcd*32+slot] (wt)
//  slot-0:     poll 32 arr -> RELEASE fence (wbl2, dirty->IF) -> garr[xcd]
//              -> poll 8 garr -> ACQUIRE fence (L2+L1 inv) -> xcdgo[xcd]
//  others:     poll xcdgo -> L1-only buffer_inv
__device__ __forceinline__ void phasebar(unsigned* sync, int xcd, int slot,
                                         unsigned target)
{
    __builtin_amdgcn_s_waitcnt(0);     // own stores acked into local L2
    __syncthreads();
    if (threadIdx.x == 0)
        __hip_atomic_store(sync + xcd * 32 + slot, target, __ATOMIC_RELAXED,
                           __HIP_MEMORY_SCOPE_AGENT);
    if (slot == 0) {
        unsigned* arr = sync + xcd * 32;
        if (threadIdx.x < 32) {
            int guard = 0;
            while (__hip_atomic_load(arr + threadIdx.x, __ATOMIC_RELAXED,
                                     __HIP_MEMORY_SCOPE_AGENT) < target) {
                __builtin_amdgcn_s_sleep(1);
                if (++guard > (1 << 18)) break;    // safety: wrong, not wedged
            }
        }
        __syncthreads();
        if (threadIdx.x < 64) {
            __builtin_amdgcn_fence(__ATOMIC_RELEASE, "agent");   // wbl2 -> IF
            asm volatile("s_waitcnt vmcnt(0) lgkmcnt(0)" ::: "memory");
            if (threadIdx.x == 0)
                __hip_atomic_store(sync + 256 + xcd * 16, target,
                                   __ATOMIC_RELAXED, __HIP_MEMORY_SCOPE_AGENT);
        }
        if (threadIdx.x < 8) {
            int guard = 0;
            while (__hip_atomic_load(sync + 256 + (int)threadIdx.x * 16,
                                     __ATOMIC_RELAXED,
                                     __HIP_MEMORY_SCOPE_AGENT) < target) {
                __builtin_amdgcn_s_sleep(1);
                if (++guard > (1 << 18)) break;
            }
        }
        __syncthreads();
        if (threadIdx.x < 64) {
            __builtin_amdgcn_fence(__ATOMIC_ACQUIRE, "agent");   // L2+L1 inv
            asm volatile("s_waitcnt vmcnt(0) lgkmcnt(0)" ::: "memory");
            if (threadIdx.x == 0)
                __hip_atomic_store(sync + 384 + xcd * 16, target,
                                   __ATOMIC_RELAXED, __HIP_MEMORY_SCOPE_AGENT);
        }
        __syncthreads();
    } else {
        if (threadIdx.x == 0) {
            int guard = 0;
            while (__hip_atomic_load(sync + 384 + xcd * 16, __ATOMIC_RELAXED,
                                     __HIP_MEMORY_SCOPE_AGENT) < target) {
                __builtin_amdgcn_s_sleep(1);
                if (++guard > (1 << 18)) break;
            }
        }
        __syncthreads();      // all waves gated until L2 is clean+fresh
        if (threadIdx.x == 0) {
            asm volatile("buffer_inv" ::: "memory");             // L1-only
            asm volatile("s_waitcnt vmcnt(0)" ::: "memory");
        }
        __syncthreads();
    }
}

#define MFMA16(A, Bv, C) __builtin_amdgcn_mfma_f32_16x16x32_f16((A), (Bv), (C), 0, 0, 0)

// ---- inline-asm ring-12 pipelined K-step machinery (R23) ------------------
#define PISSUE(I, P0, P1)                                           \
    asm volatile("global_load_dwordx4 %0, %2, off\n\t"              \
                 "global_load_dwordx4 %1, %3, off"                  \
                 : "=&v"(bf[I][0]), "=&v"(bf[I][1])                 \
                 : "v"(P0), "v"(P1) : "memory")

#define PSTEP22(I, P0, P1) do {                                     \
    half8 b0 = *(const half8*)(bp);                                 \
    half8 b1 = *(const half8*)(bp + 128);                           \
    asm volatile("s_waitcnt vmcnt(22)" ::: "memory");               \
    __builtin_amdgcn_sched_barrier(0);                              \
    acc[0][0] = MFMA16(bf[I][0], b0, acc[0][0]);                    \
    acc[0][1] = MFMA16(bf[I][0], b1, acc[0][1]);                    \
    acc[1][0] = MFMA16(bf[I][1], b0, acc[1][0]);                    \
    acc[1][1] = MFMA16(bf[I][1], b1, acc[1][1]);                    \
    bp += 1024;                                                     \
    PISSUE(I, P0, P1);                                              \
} while (0)

#define PSTEPW(I, NLIT) do {                                        \
    half8 b0 = *(const half8*)(bp);                                 \
    half8 b1 = *(const half8*)(bp + 128);                           \
    asm volatile("s_waitcnt vmcnt(" #NLIT ")" ::: "memory");        \
    __builtin_amdgcn_sched_barrier(0);                              \
    acc[0][0] = MFMA16(bf[I][0], b0, acc[0][0]);                    \
    acc[0][1] = MFMA16(bf[I][0], b1, acc[0][1]);                    \
    acc[1][0] = MFMA16(bf[I][1], b0, acc[1][0]);                    \
    acc[1][1] = MFMA16(bf[I][1], b1, acc[1][1]);                    \
    bp += 1024;                                                     \
} while (0)

__global__ void __launch_bounds__(512)
lstm_main(const _Float16* __restrict__ w1p, const _Float16* __restrict__ w0p,
          const _Float16* __restrict__ xh,
          _Float16* __restrict__ bufA, _Float16* __restrict__ bufB,
          float* __restrict__ hbF,
          const float* __restrict__ c0,
          const float* __restrict__ bih0, const float* __restrict__ bhh0,
          const float* __restrict__ bih1, const float* __restrict__ bhh1,
          const float* __restrict__ Wout, const float* __restrict__ bout,
          float* __restrict__ out, unsigned* __restrict__ sync)
{
    __shared__ _Float16 wlds[65536];   // 128 KiB

    const int tid  = threadIdx.x;
    const int lane = tid & 63;
    const int w    = tid >> 6;           // 0..7
    const int bid  = blockIdx.x;
    const int xcd  = bid & 7;
    const int slot = bid >> 3;           // 0..31
    const int isL1 = ((slot & 1) == 0);  // 16 L1 + 16 L0 blocks per XCD
    const int cb   = xcd * 16 + (slot >> 1);   // 0..127 column-block id
    const int jbase = cb * 8;
    const int jj = lane & 15;
    const int kb = lane >> 4;            // 0..3
    const int jh = jj & 7;
    const int lo = (jj < 8);
    const int rowbase = w * 32;          // wave's 32 batch rows

    // tiled h-store column index: j = jbase + jh -> tile cb>>2, col (cb&3)*8+jh
    const int jtile = cb >> 2;
    const int jcol  = (cb & 3) * 8 + jh;

    // ---- load this block's weights into LDS (once) ----
    {
        const _Float16* src = isL1 ? (w1p + (size_t)cb * 65536)
                                   : (w0p + (size_t)cb * 36864);
        const int nch = isL1 ? 8192 : 4608;   // 16B chunks
        for (int i = tid; i < nch; i += 512)
            *(half8*)&wlds[(size_t)i * 8] = *(const half8*)&src[(size_t)i * 8];
    }
    __syncthreads();

    // ---- biases + cell-state init ----
    const float* bi  = isL1 ? bih1 : bih0;
    const float* bhp = isL1 ? bhh1 : bhh0;
    float bias[4];
#pragma unroll
    for (int g = 0; g < 4; ++g)
        bias[g] = bi[g * 1024 + jbase + jh] + bhp[g * 1024 + jbase + jh];

    float cc[2][4];
#pragma unroll
    for (int mf = 0; mf < 2; ++mf)
#pragma unroll
        for (int r = 0; r < 4; ++r)
            cc[mf][r] = c0[(size_t)(rowbase + mf * 16 + kb * 4 + r) * Hq + jbase + jh];

    floatx4 acc[2][2];
    half8 bf[12][2];                     // ring: 12 slots x 2 frags = 96 VGPRs

    for (int t = -1; t <= 255; ++t) {
        const int active = isL1 ? (t >= 0) : (t < 255);
        if (active) {
#pragma unroll
            for (int mf = 0; mf < 2; ++mf)
#pragma unroll
                for (int n = 0; n < 2; ++n)
                    acc[mf][n] = (floatx4){0.f, 0.f, 0.f, 0.f};

            const _Float16* bp = wlds + kb * 256 + jj * 8;
            // per-lane tiled offset: (rowbase+jj)*32 + kb*8 -> 1KB/wave load
            const size_t loff = (size_t)(rowbase + jj) * 32 + kb * 8;

            if (isL1) {
                // gates1(t) = h_a(t)@Wih1^T + h_b(t-1)@Whh1^T  (64 K-steps)
                const _Float16* apA = bufA + (size_t)(t & 1) * BH + loff;
                const _Float16* apB = bufB + (size_t)((t + 1) & 1) * BH + loff;
#define L1P0(S) (((S) < 32) ? (apA + (size_t)(S) * 8192) : (apB + (size_t)((S) - 32) * 8192))
#define L1P1(S) (L1P0(S) + 512)
#pragma unroll
                for (int i = 0; i < 12; ++i) PISSUE(i, L1P0(i), L1P1(i));
#pragma unroll
                for (int s = 0; s < 52; ++s)
                    PSTEP22(s % 12, L1P0(s + 12), L1P1(s + 12));
                PSTEPW(4, 22);  PSTEPW(5, 20);  PSTEPW(6, 18);  PSTEPW(7, 16);
                PSTEPW(8, 14);  PSTEPW(9, 12);  PSTEPW(10, 10); PSTEPW(11, 8);
                PSTEPW(0, 6);   PSTEPW(1, 4);   PSTEPW(2, 2);   PSTEPW(3, 0);
#undef L1P0
#undef L1P1
            } else {
                // gates0(t+1) = x(t+1)@Wih0^T + h_a(t)@Whh0^T  (36 K-steps)
                const _Float16* apX = xh + (size_t)(t + 1) * 32768 + loff;
                const _Float16* apA = bufA + (size_t)(t & 1) * BH + loff;
#define L0P0(S) (((S) < 4) ? (apX + (size_t)(S) * 8192) : (apA + (size_t)((S) - 4) * 8192))
#define L0P1(S) (L0P0(S) + 512)
#pragma unroll
                for (int i = 0; i < 12; ++i) PISSUE(i, L0P0(i), L0P1(i));
#pragma unroll
                for (int s = 0; s < 24; ++s)
                    PSTEP22(s % 12, L0P0(s + 12), L0P1(s + 12));
                PSTEPW(0, 22);  PSTEPW(1, 20);  PSTEPW(2, 18);  PSTEPW(3, 16);
                PSTEPW(4, 14);  PSTEPW(5, 12);  PSTEPW(6, 10);  PSTEPW(7, 8);
                PSTEPW(8, 6);   PSTEPW(9, 4);   PSTEPW(10, 2);  PSTEPW(11, 0);
#undef L0P0
#undef L0P1
            }

            // ---- elementwise: gate-pair exchange + cell update + h store ----
            // h store: PLAIN cached store (dirty local L2; line is whole-XCD
            // private in tiled layout; made visible by phasebar's wbl2).
            _Float16* hb = isL1 ? (bufB + (size_t)(t & 1) * BH)
                                : (bufA + (size_t)((t + 1) & 1) * BH);
            unsigned* hb32 = (unsigned*)hb;
#pragma unroll
            for (int mf = 0; mf < 2; ++mf) {
#pragma unroll
                for (int r = 0; r < 4; ++r) {
                    float o0 = acc[mf][0][r];       // lo: i, hi: f
                    float o1 = acc[mf][1][r];       // lo: g, hi: o
                    float p0 = __shfl_xor(o0, 8);
                    float p1 = __shfl_xor(o1, 8);
                    float gi = (lo ? o0 : p0) + bias[0];
                    float gf = (lo ? p0 : o0) + bias[1];
                    float gg = (lo ? o1 : p1) + bias[2];
                    float go = (lo ? p1 : o1) + bias[3];
                    float ii = 1.f / (1.f + expf(-gi));
                    float ff = 1.f / (1.f + expf(-gf));
                    float gt = tanhf(gg);
                    float oo = 1.f / (1.f + expf(-go));
                    float cn = ff * cc[mf][r] + ii * gt;
                    cc[mf][r] = cn;
                    float hn = oo * tanhf(cn);

                    union { _Float16 f; unsigned short u; } cv;
                    cv.f = (_Float16)hn;
                    int prt = __shfl_xor((int)cv.u, 1);   // neighbor j^1's bits
                    int row = rowbase + mf * 16 + kb * 4 + r;
                    if (lo && ((jh & 1) == 0)) {
                        unsigned word = (unsigned)cv.u | ((unsigned)prt << 16);
                        size_t eidx = (size_t)jtile * 8192 + (size_t)row * 32 + jcol;
                        hb32[eidx >> 1] = word;
                    }
                    if (lo && isL1 && t == 255)
                        hbF[(size_t)row * Hq + jbase + jh] = hn;
                }
            }
        }

        phasebar(sync, xcd, slot, (unsigned)(t + 2));
    }

    // ---- final: out[b][o] = b_out[o] + sum_k hbF[b][k] * Wout[o][k] ----
    // (t=255 phasebar: hbF went through wbl2+inv -> cached reads are fresh)
    int gid = bid * 512 + tid;
    if (gid < Bq * 128) {
        int b = gid >> 7, o = gid & 127;
        const floatx4* hr = (const floatx4*)(hbF + (size_t)b * Hq);
        const floatx4* wr = (const floatx4*)(Wout + (size_t)o * Hq);
        float s = bout[o];
#pragma unroll 4
        for (int k = 0; k < Hq / 4; ++k) {
            floatx4 hv = hr[k], wv = wr[k];
            s += hv[0] * wv[0] + hv[1] * wv[1] + hv[2] * wv[2] + hv[3] * wv[3];
        }
        out[gid] = s;
    }
}

// ---------------------------------------------------------------------------
extern "C" void kernel_launch(void* const* d_in, const int* in_sizes, int n_in,
                              void* d_out, int out_size, void* d_ws, size_t ws_size,
                              hipStream_t stream)
{
    (void)in_sizes; (void)n_in;
    float* out = (float*)d_out;

    if (ws_size < (size_t)REQ_WS) {
        float v = -(float)(ws_size >> 20);
        hipLaunchKernelGGL(ws_sentinel_kernel, dim3((out_size + 255) / 256), dim3(256),
                           0, stream, out, out_size, v);
        return;
    }

    const float* x    = (const float*)d_in[0];
    const float* h0   = (const float*)d_in[1];
    const float* c0   = (const float*)d_in[2];
    const float* Wih0 = (const float*)d_in[3];
    const float* Whh0 = (const float*)d_in[4];
    const float* bih0 = (const float*)d_in[5];
    const float* bhh0 = (const float*)d_in[6];
    const float* Wih1 = (const float*)d_in[7];
    const float* Whh1 = (const float*)d_in[8];
    const float* bih1 = (const float*)d_in[9];
    const float* bhh1 = (const float*)d_in[10];
    const float* Wout = (const float*)d_in[11];
    const float* bout = (const float*)d_in[12];

    char* ws = (char*)d_ws;
    _Float16* w1p  = (_Float16*)(ws + OFF_W1);
    _Float16* w0p  = (_Float16*)(ws + OFF_W0);
    _Float16* xh   = (_Float16*)(ws + OFF_XH);
    _Float16* bufA = (_Float16*)(ws + OFF_BA);
    _Float16* bufB = (_Float16*)(ws + OFF_BB);
    float*    hbF  = (float*)   (ws + OFF_HF);
    unsigned* sync = (unsigned*)(ws + OFF_SY);

    long long total = N_W1 + N_W0 + N_XH + N_H;   // 21,757,952 = 84992*256
    hipLaunchKernelGGL(prep_kernel, dim3((unsigned)(total / 256)), dim3(256), 0, stream,
                       x, h0, Wih0, Whh0, Wih1, Whh1, w1p, w0p, xh, bufA, bufB, sync);

    hipLaunchKernelGGL(lstm_main, dim3(256), dim3(512), 0, stream,
                       w1p, w0p, xh, bufA, bufB, hbF, c0,
                       bih0, bhh0, bih1, bhh1, Wout, bout, out, sync);
}

// Round 25
// 5145.974 us; speedup vs baseline: 1.0405x; 1.0405x over previous
//
#include <hip/hip_runtime.h>
#include <hip/hip_fp16.h>

// ---------------------------------------------------------------------------
// 2-layer LSTM (B=256, T=256, D=128, H=1024) + final Linear(H->128).
// Persistent kernel, one phase per timestep. fp16 MFMA, fp32 accum.
// Weights in LDS; h/x coalesced tiled layout (R22); ring-12 asm pipeline
// (R23); write-through h-stores (R23 data plane).
//
// R25: DEPTH-8 h ROTATION -> FENCE-FREE ON 7/8 PHASES. h_a/h_b get 8
// rotating versions (logical slot = timestep&7, physically bit-reversed so
// adjacent logical slots are >=2MB apart). Within an 8-phase window each
// address is written once / read once and no reader re-reads an address it
// cached < 8 phases ago, so ONE global L2+L1 invalidate per 8 phases
// (t = -1,7,...,255) preserves freshness; all other phase barriers are
// pure flag handshakes (no fence, no L1 inv, no vmcnt drain).
// ---------------------------------------------------------------------------

#define Bq 256
#define Hq 1024

typedef _Float16 half8 __attribute__((ext_vector_type(8)));
typedef float    floatx4 __attribute__((ext_vector_type(4)));

#define N_W1 8388608LL   // 128 cb * 65536  ([ks64][kb4][n2][jj16][e8])
#define N_W0 4718592LL   // 128 cb * 36864  ([ks36][kb4][n2][jj16][e8])
#define N_XH 8388608LL   // T*B*D  (tiled: [t][4][256][32])
#define N_H  262144LL    // B*H
#define BH   262144

// ws byte offsets (bufA/bufB: 8 rotating slots x 512 KB each)
#define OFF_W1 0LL
#define OFF_W0 16777216LL
#define OFF_XH 26214400LL
#define OFF_BA 42991616LL
#define OFF_BB 47185920LL
#define OFF_HF 51380224LL
#define OFF_SY 52428800LL
#define REQ_WS 52430848LL   // OFF_SY + 2048  (R12 proved >=54.5MB available)

// physical slot = bit-reverse-3 of logical slot (adjacent logicals >=2MB apart)
#define REV3(s) (((((s)) & 1) << 2) | ((s) & 2) | (((s) >> 2) & 1))

// ---------------------------------------------------------------------------
__global__ void ws_sentinel_kernel(float* __restrict__ out, int n, float v)
{
    int i = blockIdx.x * blockDim.x + threadIdx.x;
    if (i < n) out[i] = v;
}

// ---------------------------------------------------------------------------
__global__ void prep_kernel(const float* __restrict__ x, const float* __restrict__ h0,
                            const float* __restrict__ Wih0, const float* __restrict__ Whh0,
                            const float* __restrict__ Wih1, const float* __restrict__ Whh1,
                            _Float16* __restrict__ w1p, _Float16* __restrict__ w0p,
                            _Float16* __restrict__ xh,
                            _Float16* __restrict__ bufA, _Float16* __restrict__ bufB,
                            unsigned* __restrict__ sync)
{
    long long gid = (long long)blockIdx.x * blockDim.x + threadIdx.x;
    if (gid < 512) sync[gid] = 0u;   // [0..255]=arr flags, [256..]=xcdgo

    if (gid < N_W1) {
        // [cb][ks][kb][n][jj][e]; gate-col row = (2n + jj>>3)*1024 + cb*8 + (jj&7)
        long long i = gid;
        int e  = (int)(i & 7);
        int jj = (int)((i >> 3) & 15);
        int n  = (int)((i >> 7) & 1);
        int kb = (int)((i >> 8) & 3);
        int ks = (int)((i >> 10) & 63);
        int cb = (int)(i >> 16);
        int row = (2 * n + (jj >> 3)) * 1024 + cb * 8 + (jj & 7);
        int k = ks * 32 + kb * 8 + e;
        float v = (k < 1024) ? Wih1[(size_t)row * 1024 + k]
                             : Whh1[(size_t)row * 1024 + (k - 1024)];
        w1p[i] = (_Float16)v;
    } else if (gid < N_W1 + N_W0) {
        long long i = gid - N_W1;
        int cb = (int)(i / 36864LL);
        int r  = (int)(i - (long long)cb * 36864LL);
        int ks = r >> 10;
        int kb = (r >> 8) & 3;
        int n  = (r >> 7) & 1;
        int jj = (r >> 3) & 15;
        int e  = r & 7;
        int row = (2 * n + (jj >> 3)) * 1024 + cb * 8 + (jj & 7);
        int k = ks * 32 + kb * 8 + e;
        float v = (k < 128) ? Wih0[(size_t)row * 128 + k]
                            : Whh0[(size_t)row * 1024 + (k - 128)];
        w0p[i] = (_Float16)v;
    } else if (gid < N_W1 + N_W0 + N_XH) {
        long long i = gid - N_W1 - N_W0;
        // xh tiled: [t][tile4][b][32]; element d = tile*32+e of x[b][t][:]
        int t    = (int)(i >> 15);
        int rem  = (int)(i & 32767);
        int tile = rem >> 13;
        int b    = (rem >> 5) & 255;
        int e    = rem & 31;
        int d    = tile * 32 + e;
        xh[i] = (_Float16)x[((size_t)b * 256 + t) * 128 + d];
    } else if (gid < N_W1 + N_W0 + N_XH + N_H) {
        long long i = gid - N_W1 - N_W0 - N_XH;
        // h0 is [row][H]; tiled dest idx = (j>>5)*8192 + row*32 + (j&31)
        int row = (int)(i >> 10);
        int j   = (int)(i & 1023);
        size_t idx = (size_t)(j >> 5) * 8192 + (size_t)row * 32 + (j & 31);
        _Float16 v = (_Float16)h0[i];
        // h(-1) lives in logical slot 7 -> physical REV3(7)=7
        bufA[(size_t)7 * BH + idx] = v;
        bufB[(size_t)7 * BH + idx] = v;
    }
}

// ---------------------------------------------------------------------------
// Merged phase barrier (R23) with CONDITIONAL invalidate.
//  all blocks: drain wt stores, publish flags[bid]
//  slot-0:     poll 256 flags -> [acquire L2+L1 inv if doinv] -> xcdgo
//  others:     poll xcdgo -> [L1-only buffer_inv if doinv]
__device__ __forceinline__ void phasebar(unsigned* flags, unsigned* xcdgo,
                                         int bid, int slot, unsigned target,
                                         int doinv)
{
    __builtin_amdgcn_s_waitcnt(0);     // own write-through stores at IF
    __syncthreads();
    if (threadIdx.x == 0)
        __hip_atomic_store(flags + bid, target, __ATOMIC_RELAXED,
                           __HIP_MEMORY_SCOPE_AGENT);
    if (slot == 0) {
        if (threadIdx.x < 256) {
            int guard = 0;
            while (__hip_atomic_load(flags + threadIdx.x, __ATOMIC_RELAXED,
                                     __HIP_MEMORY_SCOPE_AGENT) < target) {
                __builtin_amdgcn_s_sleep(1);
                if (++guard > (1 << 18)) break;    // safety: wrong, not wedged
            }
        }
        __syncthreads();
        if (threadIdx.x < 64) {
            if (doinv) {
                __builtin_amdgcn_fence(__ATOMIC_ACQUIRE, "agent");  // L2+L1 inv
                asm volatile("s_waitcnt vmcnt(0) lgkmcnt(0)" ::: "memory");
            }
            if (threadIdx.x == 0)
                __hip_atomic_store(xcdgo, target, __ATOMIC_RELAXED,
                                   __HIP_MEMORY_SCOPE_AGENT);
        }
        __syncthreads();
    } else {
        if (threadIdx.x == 0) {
            int guard = 0;
            while (__hip_atomic_load(xcdgo, __ATOMIC_RELAXED,
                                     __HIP_MEMORY_SCOPE_AGENT) < target) {
                __builtin_amdgcn_s_sleep(1);
                if (++guard > (1 << 18)) break;
            }
        }
        __syncthreads();
        if (doinv) {
            if (threadIdx.x == 0) {
                asm volatile("buffer_inv" ::: "memory");            // L1-only
                asm volatile("s_waitcnt vmcnt(0)" ::: "memory");
            }
            __syncthreads();
        }
    }
}

#define MFMA16(A, Bv, C) __builtin_amdgcn_mfma_f32_16x16x32_f16((A), (Bv), (C), 0, 0, 0)

// ---- inline-asm ring-12 pipelined K-step machinery (R23) ------------------
#define PISSUE(I, P0, P1)                                           \
    asm volatile("global_load_dwordx4 %0, %2, off\n\t"              \
                 "global_load_dwordx4 %1, %3, off"                  \
                 : "=&v"(bf[I][0]), "=&v"(bf[I][1])                 \
                 : "v"(P0), "v"(P1) : "memory")

#define PSTEP22(I, P0, P1) do {                                     \
    half8 b0 = *(const half8*)(bp);                                 \
    half8 b1 = *(const half8*)(bp + 128);                           \
    asm volatile("s_waitcnt vmcnt(22)" ::: "memory");               \
    __builtin_amdgcn_sched_barrier(0);                              \
    acc[0][0] = MFMA16(bf[I][0], b0, acc[0][0]);                    \
    acc[0][1] = MFMA16(bf[I][0], b1, acc[0][1]);                    \
    acc[1][0] = MFMA16(bf[I][1], b0, acc[1][0]);                    \
    acc[1][1] = MFMA16(bf[I][1], b1, acc[1][1]);                    \
    bp += 1024;                                                     \
    PISSUE(I, P0, P1);                                              \
} while (0)

#define PSTEPW(I, NLIT) do {                                        \
    half8 b0 = *(const half8*)(bp);                                 \
    half8 b1 = *(const half8*)(bp + 128);                           \
    asm volatile("s_waitcnt vmcnt(" #NLIT ")" ::: "memory");        \
    __builtin_amdgcn_sched_barrier(0);                              \
    acc[0][0] = MFMA16(bf[I][0], b0, acc[0][0]);                    \
    acc[0][1] = MFMA16(bf[I][0], b1, acc[0][1]);                    \
    acc[1][0] = MFMA16(bf[I][1], b0, acc[1][0]);                    \
    acc[1][1] = MFMA16(bf[I][1], b1, acc[1][1]);                    \
    bp += 1024;                                                     \
} while (0)

__global__ void __launch_bounds__(512)
lstm_main(const _Float16* __restrict__ w1p, const _Float16* __restrict__ w0p,
          const _Float16* __restrict__ xh,
          _Float16* __restrict__ bufA, _Float16* __restrict__ bufB,
          float* __restrict__ hbF,
          const float* __restrict__ c0,
          const float* __restrict__ bih0, const float* __restrict__ bhh0,
          const float* __restrict__ bih1, const float* __restrict__ bhh1,
          const float* __restrict__ Wout, const float* __restrict__ bout,
          float* __restrict__ out, unsigned* __restrict__ sync)
{
    __shared__ _Float16 wlds[65536];   // 128 KiB

    const int tid  = threadIdx.x;
    const int lane = tid & 63;
    const int w    = tid >> 6;           // 0..7
    const int bid  = blockIdx.x;
    const int xcd  = bid & 7;
    const int slot = bid >> 3;           // 0..31
    const int isL1 = ((slot & 1) == 0);  // 16 L1 + 16 L0 blocks per XCD
    const int cb   = xcd * 16 + (slot >> 1);   // 0..127 column-block id
    const int jbase = cb * 8;
    const int jj = lane & 15;
    const int kb = lane >> 4;            // 0..3
    const int jh = jj & 7;
    const int lo = (jj < 8);
    const int rowbase = w * 32;          // wave's 32 batch rows

    unsigned* xcdgo = sync + 256 + xcd * 16;   // 64B-separated per-XCD flags

    // tiled h-store column index: j = jbase + jh -> tile cb>>2, col (cb&3)*8+jh
    const int jtile = cb >> 2;
    const int jcol  = (cb & 3) * 8 + jh;

    // ---- load this block's weights into LDS (once) ----
    {
        const _Float16* src = isL1 ? (w1p + (size_t)cb * 65536)
                                   : (w0p + (size_t)cb * 36864);
        const int nch = isL1 ? 8192 : 4608;   // 16B chunks
        for (int i = tid; i < nch; i += 512)
            *(half8*)&wlds[(size_t)i * 8] = *(const half8*)&src[(size_t)i * 8];
    }
    __syncthreads();

    // ---- biases + cell-state init ----
    const float* bi  = isL1 ? bih1 : bih0;
    const float* bhp = isL1 ? bhh1 : bhh0;
    float bias[4];
#pragma unroll
    for (int g = 0; g < 4; ++g)
        bias[g] = bi[g * 1024 + jbase + jh] + bhp[g * 1024 + jbase + jh];

    float cc[2][4];
#pragma unroll
    for (int mf = 0; mf < 2; ++mf)
#pragma unroll
        for (int r = 0; r < 4; ++r)
            cc[mf][r] = c0[(size_t)(rowbase + mf * 16 + kb * 4 + r) * Hq + jbase + jh];

    floatx4 acc[2][2];
    half8 bf[12][2];                     // ring: 12 slots x 2 frags = 96 VGPRs

    for (int t = -1; t <= 255; ++t) {
        const int active = isL1 ? (t >= 0) : (t < 255);
        if (active) {
#pragma unroll
            for (int mf = 0; mf < 2; ++mf)
#pragma unroll
                for (int n = 0; n < 2; ++n)
                    acc[mf][n] = (floatx4){0.f, 0.f, 0.f, 0.f};

            const _Float16* bp = wlds + kb * 256 + jj * 8;
            // per-lane tiled offset: (rowbase+jj)*32 + kb*8 -> 1KB/wave load
            const size_t loff = (size_t)(rowbase + jj) * 32 + kb * 8;

            // rotating h slots (physical = REV3(logical))
            const int sA = REV3(t & 7);          // h_a(t)
            const int sB = REV3((t + 7) & 7);    // h_b(t-1)

            if (isL1) {
                // gates1(t) = h_a(t)@Wih1^T + h_b(t-1)@Whh1^T  (64 K-steps)
                const _Float16* apA = bufA + (size_t)sA * BH + loff;
                const _Float16* apB = bufB + (size_t)sB * BH + loff;
#define L1P0(S) (((S) < 32) ? (apA + (size_t)(S) * 8192) : (apB + (size_t)((S) - 32) * 8192))
#define L1P1(S) (L1P0(S) + 512)
#pragma unroll
                for (int i = 0; i < 12; ++i) PISSUE(i, L1P0(i), L1P1(i));
#pragma unroll
                for (int s = 0; s < 52; ++s)
                    PSTEP22(s % 12, L1P0(s + 12), L1P1(s + 12));
                PSTEPW(4, 22);  PSTEPW(5, 20);  PSTEPW(6, 18);  PSTEPW(7, 16);
                PSTEPW(8, 14);  PSTEPW(9, 12);  PSTEPW(10, 10); PSTEPW(11, 8);
                PSTEPW(0, 6);   PSTEPW(1, 4);   PSTEPW(2, 2);   PSTEPW(3, 0);
#undef L1P0
#undef L1P1
            } else {
                // gates0(t+1) = x(t+1)@Wih0^T + h_a(t)@Whh0^T  (36 K-steps)
                const _Float16* apX = xh + (size_t)(t + 1) * 32768 + loff;
                const _Float16* apA = bufA + (size_t)sA * BH + loff;
#define L0P0(S) (((S) < 4) ? (apX + (size_t)(S) * 8192) : (apA + (size_t)((S) - 4) * 8192))
#define L0P1(S) (L0P0(S) + 512)
#pragma unroll
                for (int i = 0; i < 12; ++i) PISSUE(i, L0P0(i), L0P1(i));
#pragma unroll
                for (int s = 0; s < 24; ++s)
                    PSTEP22(s % 12, L0P0(s + 12), L0P1(s + 12));
                PSTEPW(0, 22);  PSTEPW(1, 20);  PSTEPW(2, 18);  PSTEPW(3, 16);
                PSTEPW(4, 14);  PSTEPW(5, 12);  PSTEPW(6, 10);  PSTEPW(7, 8);
                PSTEPW(8, 6);   PSTEPW(9, 4);   PSTEPW(10, 2);  PSTEPW(11, 0);
#undef L0P0
#undef L0P1
            }

            // ---- elementwise: gate-pair exchange + cell update + h store ----
            // write-through stores to rotating destination slot
            const int sW = isL1 ? REV3(t & 7) : REV3((t + 1) & 7);
            _Float16* hb = isL1 ? (bufB + (size_t)sW * BH)
                                : (bufA + (size_t)sW * BH);
            unsigned* hb32 = (unsigned*)hb;
#pragma unroll
            for (int mf = 0; mf < 2; ++mf) {
#pragma unroll
                for (int r = 0; r < 4; ++r) {
                    float o0 = acc[mf][0][r];       // lo: i, hi: f
                    float o1 = acc[mf][1][r];       // lo: g, hi: o
                    float p0 = __shfl_xor(o0, 8);
                    float p1 = __shfl_xor(o1, 8);
                    float gi = (lo ? o0 : p0) + bias[0];
                    float gf = (lo ? p0 : o0) + bias[1];
                    float gg = (lo ? o1 : p1) + bias[2];
                    float go = (lo ? p1 : o1) + bias[3];
                    float ii = 1.f / (1.f + expf(-gi));
                    float ff = 1.f / (1.f + expf(-gf));
                    float gt = tanhf(gg);
                    float oo = 1.f / (1.f + expf(-go));
                    float cn = ff * cc[mf][r] + ii * gt;
                    cc[mf][r] = cn;
                    float hn = oo * tanhf(cn);

                    union { _Float16 f; unsigned short u; } cv;
                    cv.f = (_Float16)hn;
                    int prt = __shfl_xor((int)cv.u, 1);   // neighbor j^1's bits
                    int row = rowbase + mf * 16 + kb * 4 + r;
                    if (lo && ((jh & 1) == 0)) {
                        unsigned word = (unsigned)cv.u | ((unsigned)prt << 16);
                        size_t eidx = (size_t)jtile * 8192 + (size_t)row * 32 + jcol;
                        __hip_atomic_store(hb32 + (eidx >> 1), word,
                                           __ATOMIC_RELAXED,
                                           __HIP_MEMORY_SCOPE_AGENT);
                    }
                    if (lo && isL1 && t == 255)
                        __hip_atomic_store(hbF + (size_t)row * Hq + jbase + jh,
                                           hn, __ATOMIC_RELAXED,
                                           __HIP_MEMORY_SCOPE_AGENT);
                }
            }
        }

        // invalidate once per 8 phases: t = -1, 7, 15, ..., 255
        phasebar(sync, xcdgo, bid, slot, (unsigned)(t + 2),
                 (((t + 1) & 7) == 0));
    }

    // ---- final: out[b][o] = b_out[o] + sum_k hbF[b][k] * Wout[o][k] ----
    // (t=255 phasebar ran the inv -> hbF cached reads are fresh)
    int gid = bid * 512 + tid;
    if (gid < Bq * 128) {
        int b = gid >> 7, o = gid & 127;
        const floatx4* hr = (const floatx4*)(hbF + (size_t)b * Hq);
        const floatx4* wr = (const floatx4*)(Wout + (size_t)o * Hq);
        float s = bout[o];
#pragma unroll 4
        for (int k = 0; k < Hq / 4; ++k) {
            floatx4 hv = hr[k], wv = wr[k];
            s += hv[0] * wv[0] + hv[1] * wv[1] + hv[2] * wv[2] + hv[3] * wv[3];
        }
        out[gid] = s;
    }
}

// ---------------------------------------------------------------------------
extern "C" void kernel_launch(void* const* d_in, const int* in_sizes, int n_in,
                              void* d_out, int out_size, void* d_ws, size_t ws_size,
                              hipStream_t stream)
{
    (void)in_sizes; (void)n_in;
    float* out = (float*)d_out;

    if (ws_size < (size_t)REQ_WS) {
        float v = -(float)(ws_size >> 20);
        hipLaunchKernelGGL(ws_sentinel_kernel, dim3((out_size + 255) / 256), dim3(256),
                           0, stream, out, out_size, v);
        return;
    }

    const float* x    = (const float*)d_in[0];
    const float* h0   = (const float*)d_in[1];
    const float* c0   = (const float*)d_in[2];
    const float* Wih0 = (const float*)d_in[3];
    const float* Whh0 = (const float*)d_in[4];
    const float* bih0 = (const float*)d_in[5];
    const float* bhh0 = (const float*)d_in[6];
    const float* Wih1 = (const float*)d_in[7];
    const float* Whh1 = (const float*)d_in[8];
    const float* bih1 = (const float*)d_in[9];
    const float* bhh1 = (const float*)d_in[10];
    const float* Wout = (const float*)d_in[11];
    const float* bout = (const float*)d_in[12];

    char* ws = (char*)d_ws;
    _Float16* w1p  = (_Float16*)(ws + OFF_W1);
    _Float16* w0p  = (_Float16*)(ws + OFF_W0);
    _Float16* xh   = (_Float16*)(ws + OFF_XH);
    _Float16* bufA = (_Float16*)(ws + OFF_BA);
    _Float16* bufB = (_Float16*)(ws + OFF_BB);
    float*    hbF  = (float*)   (ws + OFF_HF);
    unsigned* sync = (unsigned*)(ws + OFF_SY);

    long long total = N_W1 + N_W0 + N_XH + N_H;   // 21,757,952 = 84992*256
    hipLaunchKernelGGL(prep_kernel, dim3((unsigned)(total / 256)), dim3(256), 0, stream,
                       x, h0, Wih0, Whh0, Wih1, Whh1, w1p, w0p, xh, bufA, bufB, sync);

    hipLaunchKernelGGL(lstm_main, dim3(256), dim3(512), 0, stream,
                       w1p, w0p, xh, bufA, bufB, hbF, c0,
                       bih0, bhh0, bih1, bhh1, Wout, bout, out, sync);
}

// Round 26
// 4846.098 us; speedup vs baseline: 1.1049x; 1.0619x over previous
//
#include <hip/hip_runtime.h>
#include <hip/hip_fp16.h>

// ---------------------------------------------------------------------------
// 2-layer LSTM (B=256, T=256, D=128, H=1024) + final Linear(H->128).
// Persistent kernel, one phase per timestep. fp16 MFMA, fp32 accum.
// Weights in LDS; h/x coalesced tiled layout (R22); ring-12 asm pipeline
// (R23); depth-8 h rotation + 1-in-8 invalidate (R25).
//
// R26: HW TRANSCENDENTALS in the elementwise tail. sigmoid/tanh via
// quarter-rate v_exp_f32 (2^x) + v_rcp_f32 instead of libm expf/tanhf
// (~5x fewer VALU ops on the serial post-GEMM tail).
// ---------------------------------------------------------------------------

#define Bq 256
#define Hq 1024

typedef _Float16 half8 __attribute__((ext_vector_type(8)));
typedef float    floatx4 __attribute__((ext_vector_type(4)));

#define N_W1 8388608LL   // 128 cb * 65536  ([ks64][kb4][n2][jj16][e8])
#define N_W0 4718592LL   // 128 cb * 36864  ([ks36][kb4][n2][jj16][e8])
#define N_XH 8388608LL   // T*B*D  (tiled: [t][4][256][32])
#define N_H  262144LL    // B*H
#define BH   262144

// ws byte offsets (bufA/bufB: 8 rotating slots x 512 KB each)
#define OFF_W1 0LL
#define OFF_W0 16777216LL
#define OFF_XH 26214400LL
#define OFF_BA 42991616LL
#define OFF_BB 47185920LL
#define OFF_HF 51380224LL
#define OFF_SY 52428800LL
#define REQ_WS 52430848LL   // OFF_SY + 2048

// physical slot = bit-reverse-3 of logical slot (adjacent logicals >=2MB apart)
#define REV3(s) (((((s)) & 1) << 2) | ((s) & 2) | (((s) >> 2) & 1))

// ---------------------------------------------------------------------------
__global__ void ws_sentinel_kernel(float* __restrict__ out, int n, float v)
{
    int i = blockIdx.x * blockDim.x + threadIdx.x;
    if (i < n) out[i] = v;
}

// ---------------------------------------------------------------------------
__global__ void prep_kernel(const float* __restrict__ x, const float* __restrict__ h0,
                            const float* __restrict__ Wih0, const float* __restrict__ Whh0,
                            const float* __restrict__ Wih1, const float* __restrict__ Whh1,
                            _Float16* __restrict__ w1p, _Float16* __restrict__ w0p,
                            _Float16* __restrict__ xh,
                            _Float16* __restrict__ bufA, _Float16* __restrict__ bufB,
                            unsigned* __restrict__ sync)
{
    long long gid = (long long)blockIdx.x * blockDim.x + threadIdx.x;
    if (gid < 512) sync[gid] = 0u;   // [0..255]=arr flags, [256..]=xcdgo

    if (gid < N_W1) {
        // [cb][ks][kb][n][jj][e]; gate-col row = (2n + jj>>3)*1024 + cb*8 + (jj&7)
        long long i = gid;
        int e  = (int)(i & 7);
        int jj = (int)((i >> 3) & 15);
        int n  = (int)((i >> 7) & 1);
        int kb = (int)((i >> 8) & 3);
        int ks = (int)((i >> 10) & 63);
        int cb = (int)(i >> 16);
        int row = (2 * n + (jj >> 3)) * 1024 + cb * 8 + (jj & 7);
        int k = ks * 32 + kb * 8 + e;
        float v = (k < 1024) ? Wih1[(size_t)row * 1024 + k]
                             : Whh1[(size_t)row * 1024 + (k - 1024)];
        w1p[i] = (_Float16)v;
    } else if (gid < N_W1 + N_W0) {
        long long i = gid - N_W1;
        int cb = (int)(i / 36864LL);
        int r  = (int)(i - (long long)cb * 36864LL);
        int ks = r >> 10;
        int kb = (r >> 8) & 3;
        int n  = (r >> 7) & 1;
        int jj = (r >> 3) & 15;
        int e  = r & 7;
        int row = (2 * n + (jj >> 3)) * 1024 + cb * 8 + (jj & 7);
        int k = ks * 32 + kb * 8 + e;
        float v = (k < 128) ? Wih0[(size_t)row * 128 + k]
                            : Whh0[(size_t)row * 1024 + (k - 128)];
        w0p[i] = (_Float16)v;
    } else if (gid < N_W1 + N_W0 + N_XH) {
        long long i = gid - N_W1 - N_W0;
        // xh tiled: [t][tile4][b][32]; element d = tile*32+e of x[b][t][:]
        int t    = (int)(i >> 15);
        int rem  = (int)(i & 32767);
        int tile = rem >> 13;
        int b    = (rem >> 5) & 255;
        int e    = rem & 31;
        int d    = tile * 32 + e;
        xh[i] = (_Float16)x[((size_t)b * 256 + t) * 128 + d];
    } else if (gid < N_W1 + N_W0 + N_XH + N_H) {
        long long i = gid - N_W1 - N_W0 - N_XH;
        // h0 is [row][H]; tiled dest idx = (j>>5)*8192 + row*32 + (j&31)
        int row = (int)(i >> 10);
        int j   = (int)(i & 1023);
        size_t idx = (size_t)(j >> 5) * 8192 + (size_t)row * 32 + (j & 31);
        _Float16 v = (_Float16)h0[i];
        // h(-1) lives in logical slot 7 -> physical REV3(7)=7
        bufA[(size_t)7 * BH + idx] = v;
        bufB[(size_t)7 * BH + idx] = v;
    }
}

// ---------------------------------------------------------------------------
// Merged phase barrier (R23) with CONDITIONAL invalidate (R25).
__device__ __forceinline__ void phasebar(unsigned* flags, unsigned* xcdgo,
                                         int bid, int slot, unsigned target,
                                         int doinv)
{
    __builtin_amdgcn_s_waitcnt(0);     // own write-through stores at IF
    __syncthreads();
    if (threadIdx.x == 0)
        __hip_atomic_store(flags + bid, target, __ATOMIC_RELAXED,
                           __HIP_MEMORY_SCOPE_AGENT);
    if (slot == 0) {
        if (threadIdx.x < 256) {
            int guard = 0;
            while (__hip_atomic_load(flags + threadIdx.x, __ATOMIC_RELAXED,
                                     __HIP_MEMORY_SCOPE_AGENT) < target) {
                __builtin_amdgcn_s_sleep(1);
                if (++guard > (1 << 18)) break;    // safety: wrong, not wedged
            }
        }
        __syncthreads();
        if (threadIdx.x < 64) {
            if (doinv) {
                __builtin_amdgcn_fence(__ATOMIC_ACQUIRE, "agent");  // L2+L1 inv
                asm volatile("s_waitcnt vmcnt(0) lgkmcnt(0)" ::: "memory");
            }
            if (threadIdx.x == 0)
                __hip_atomic_store(xcdgo, target, __ATOMIC_RELAXED,
                                   __HIP_MEMORY_SCOPE_AGENT);
        }
        __syncthreads();
    } else {
        if (threadIdx.x == 0) {
            int guard = 0;
            while (__hip_atomic_load(xcdgo, __ATOMIC_RELAXED,
                                     __HIP_MEMORY_SCOPE_AGENT) < target) {
                __builtin_amdgcn_s_sleep(1);
                if (++guard > (1 << 18)) break;
            }
        }
        __syncthreads();
        if (doinv) {
            if (threadIdx.x == 0) {
                asm volatile("buffer_inv" ::: "memory");            // L1-only
                asm volatile("s_waitcnt vmcnt(0)" ::: "memory");
            }
            __syncthreads();
        }
    }
}

// ---- HW transcendentals ---------------------------------------------------
__device__ __forceinline__ float fexp2(float x)
{ float r; asm("v_exp_f32 %0, %1" : "=v"(r) : "v"(x)); return r; }
__device__ __forceinline__ float frcp(float x)
{ float r; asm("v_rcp_f32 %0, %1" : "=v"(r) : "v"(x)); return r; }
// sigmoid(x) = 1/(1+e^-x) = 1/(1+2^(-x*log2e))
__device__ __forceinline__ float fsig(float x)
{ return frcp(1.0f + fexp2(x * -1.44269504f)); }
// tanh(x) = 1 - 2/(e^(2x)+1) = 1 - 2/(2^(x*2*log2e)+1)
__device__ __forceinline__ float ftanhf_(float x)
{ return 1.0f - 2.0f * frcp(1.0f + fexp2(x * 2.88539008f)); }

#define MFMA16(A, Bv, C) __builtin_amdgcn_mfma_f32_16x16x32_f16((A), (Bv), (C), 0, 0, 0)

// ---- inline-asm ring-12 pipelined K-step machinery (R23) ------------------
#define PISSUE(I, P0, P1)                                           \
    asm volatile("global_load_dwordx4 %0, %2, off\n\t"              \
                 "global_load_dwordx4 %1, %3, off"                  \
                 : "=&v"(bf[I][0]), "=&v"(bf[I][1])                 \
                 : "v"(P0), "v"(P1) : "memory")

#define PSTEP22(I, P0, P1) do {                                     \
    half8 b0 = *(const half8*)(bp);                                 \
    half8 b1 = *(const half8*)(bp + 128);                           \
    asm volatile("s_waitcnt vmcnt(22)" ::: "memory");               \
    __builtin_amdgcn_sched_barrier(0);                              \
    acc[0][0] = MFMA16(bf[I][0], b0, acc[0][0]);                    \
    acc[0][1] = MFMA16(bf[I][0], b1, acc[0][1]);                    \
    acc[1][0] = MFMA16(bf[I][1], b0, acc[1][0]);                    \
    acc[1][1] = MFMA16(bf[I][1], b1, acc[1][1]);                    \
    bp += 1024;                                                     \
    PISSUE(I, P0, P1);                                              \
} while (0)

#define PSTEPW(I, NLIT) do {                                        \
    half8 b0 = *(const half8*)(bp);                                 \
    half8 b1 = *(const half8*)(bp + 128);                           \
    asm volatile("s_waitcnt vmcnt(" #NLIT ")" ::: "memory");        \
    __builtin_amdgcn_sched_barrier(0);                              \
    acc[0][0] = MFMA16(bf[I][0], b0, acc[0][0]);                    \
    acc[0][1] = MFMA16(bf[I][0], b1, acc[0][1]);                    \
    acc[1][0] = MFMA16(bf[I][1], b0, acc[1][0]);                    \
    acc[1][1] = MFMA16(bf[I][1], b1, acc[1][1]);                    \
    bp += 1024;                                                     \
} while (0)

__global__ void __launch_bounds__(512)
lstm_main(const _Float16* __restrict__ w1p, const _Float16* __restrict__ w0p,
          const _Float16* __restrict__ xh,
          _Float16* __restrict__ bufA, _Float16* __restrict__ bufB,
          float* __restrict__ hbF,
          const float* __restrict__ c0,
          const float* __restrict__ bih0, const float* __restrict__ bhh0,
          const float* __restrict__ bih1, const float* __restrict__ bhh1,
          const float* __restrict__ Wout, const float* __restrict__ bout,
          float* __restrict__ out, unsigned* __restrict__ sync)
{
    __shared__ _Float16 wlds[65536];   // 128 KiB

    const int tid  = threadIdx.x;
    const int lane = tid & 63;
    const int w    = tid >> 6;           // 0..7
    const int bid  = blockIdx.x;
    const int xcd  = bid & 7;
    const int slot = bid >> 3;           // 0..31
    const int isL1 = ((slot & 1) == 0);  // 16 L1 + 16 L0 blocks per XCD
    const int cb   = xcd * 16 + (slot >> 1);   // 0..127 column-block id
    const int jbase = cb * 8;
    const int jj = lane & 15;
    const int kb = lane >> 4;            // 0..3
    const int jh = jj & 7;
    const int lo = (jj < 8);
    const int rowbase = w * 32;          // wave's 32 batch rows

    unsigned* xcdgo = sync + 256 + xcd * 16;   // 64B-separated per-XCD flags

    // tiled h-store column index: j = jbase + jh -> tile cb>>2, col (cb&3)*8+jh
    const int jtile = cb >> 2;
    const int jcol  = (cb & 3) * 8 + jh;

    // ---- load this block's weights into LDS (once) ----
    {
        const _Float16* src = isL1 ? (w1p + (size_t)cb * 65536)
                                   : (w0p + (size_t)cb * 36864);
        const int nch = isL1 ? 8192 : 4608;   // 16B chunks
        for (int i = tid; i < nch; i += 512)
            *(half8*)&wlds[(size_t)i * 8] = *(const half8*)&src[(size_t)i * 8];
    }
    __syncthreads();

    // ---- biases + cell-state init ----
    const float* bi  = isL1 ? bih1 : bih0;
    const float* bhp = isL1 ? bhh1 : bhh0;
    float bias[4];
#pragma unroll
    for (int g = 0; g < 4; ++g)
        bias[g] = bi[g * 1024 + jbase + jh] + bhp[g * 1024 + jbase + jh];

    float cc[2][4];
#pragma unroll
    for (int mf = 0; mf < 2; ++mf)
#pragma unroll
        for (int r = 0; r < 4; ++r)
            cc[mf][r] = c0[(size_t)(rowbase + mf * 16 + kb * 4 + r) * Hq + jbase + jh];

    floatx4 acc[2][2];
    half8 bf[12][2];                     // ring: 12 slots x 2 frags = 96 VGPRs

    for (int t = -1; t <= 255; ++t) {
        const int active = isL1 ? (t >= 0) : (t < 255);
        if (active) {
#pragma unroll
            for (int mf = 0; mf < 2; ++mf)
#pragma unroll
                for (int n = 0; n < 2; ++n)
                    acc[mf][n] = (floatx4){0.f, 0.f, 0.f, 0.f};

            const _Float16* bp = wlds + kb * 256 + jj * 8;
            // per-lane tiled offset: (rowbase+jj)*32 + kb*8 -> 1KB/wave load
            const size_t loff = (size_t)(rowbase + jj) * 32 + kb * 8;

            // rotating h slots (physical = REV3(logical))
            const int sA = REV3(t & 7);          // h_a(t)
            const int sB = REV3((t + 7) & 7);    // h_b(t-1)

            if (isL1) {
                // gates1(t) = h_a(t)@Wih1^T + h_b(t-1)@Whh1^T  (64 K-steps)
                const _Float16* apA = bufA + (size_t)sA * BH + loff;
                const _Float16* apB = bufB + (size_t)sB * BH + loff;
#define L1P0(S) (((S) < 32) ? (apA + (size_t)(S) * 8192) : (apB + (size_t)((S) - 32) * 8192))
#define L1P1(S) (L1P0(S) + 512)
#pragma unroll
                for (int i = 0; i < 12; ++i) PISSUE(i, L1P0(i), L1P1(i));
#pragma unroll
                for (int s = 0; s < 52; ++s)
                    PSTEP22(s % 12, L1P0(s + 12), L1P1(s + 12));
                PSTEPW(4, 22);  PSTEPW(5, 20);  PSTEPW(6, 18);  PSTEPW(7, 16);
                PSTEPW(8, 14);  PSTEPW(9, 12);  PSTEPW(10, 10); PSTEPW(11, 8);
                PSTEPW(0, 6);   PSTEPW(1, 4);   PSTEPW(2, 2);   PSTEPW(3, 0);
#undef L1P0
#undef L1P1
            } else {
                // gates0(t+1) = x(t+1)@Wih0^T + h_a(t)@Whh0^T  (36 K-steps)
                const _Float16* apX = xh + (size_t)(t + 1) * 32768 + loff;
                const _Float16* apA = bufA + (size_t)sA * BH + loff;
#define L0P0(S) (((S) < 4) ? (apX + (size_t)(S) * 8192) : (apA + (size_t)((S) - 4) * 8192))
#define L0P1(S) (L0P0(S) + 512)
#pragma unroll
                for (int i = 0; i < 12; ++i) PISSUE(i, L0P0(i), L0P1(i));
#pragma unroll
                for (int s = 0; s < 24; ++s)
                    PSTEP22(s % 12, L0P0(s + 12), L0P1(s + 12));
                PSTEPW(0, 22);  PSTEPW(1, 20);  PSTEPW(2, 18);  PSTEPW(3, 16);
                PSTEPW(4, 14);  PSTEPW(5, 12);  PSTEPW(6, 10);  PSTEPW(7, 8);
                PSTEPW(8, 6);   PSTEPW(9, 4);   PSTEPW(10, 2);  PSTEPW(11, 0);
#undef L0P0
#undef L0P1
            }

            // ---- elementwise: gate-pair exchange + cell update + h store ----
            const int sW = isL1 ? REV3(t & 7) : REV3((t + 1) & 7);
            _Float16* hb = isL1 ? (bufB + (size_t)sW * BH)
                                : (bufA + (size_t)sW * BH);
            unsigned* hb32 = (unsigned*)hb;
#pragma unroll
            for (int mf = 0; mf < 2; ++mf) {
#pragma unroll
                for (int r = 0; r < 4; ++r) {
                    float o0 = acc[mf][0][r];       // lo: i, hi: f
                    float o1 = acc[mf][1][r];       // lo: g, hi: o
                    float p0 = __shfl_xor(o0, 8);
                    float p1 = __shfl_xor(o1, 8);
                    float gi = (lo ? o0 : p0) + bias[0];
                    float gf = (lo ? p0 : o0) + bias[1];
                    float gg = (lo ? o1 : p1) + bias[2];
                    float go = (lo ? p1 : o1) + bias[3];
                    float ii = fsig(gi);
                    float ff = fsig(gf);
                    float gt = ftanhf_(gg);
                    float oo = fsig(go);
                    float cn = ff * cc[mf][r] + ii * gt;
                    cc[mf][r] = cn;
                    float hn = oo * ftanhf_(cn);

                    union { _Float16 f; unsigned short u; } cv;
                    cv.f = (_Float16)hn;
                    int prt = __shfl_xor((int)cv.u, 1);   // neighbor j^1's bits
                    int row = rowbase + mf * 16 + kb * 4 + r;
                    if (lo && ((jh & 1) == 0)) {
                        unsigned word = (unsigned)cv.u | ((unsigned)prt << 16);
                        size_t eidx = (size_t)jtile * 8192 + (size_t)row * 32 + jcol;
                        __hip_atomic_store(hb32 + (eidx >> 1), word,
                                           __ATOMIC_RELAXED,
                                           __HIP_MEMORY_SCOPE_AGENT);
                    }
                    if (lo && isL1 && t == 255)
                        __hip_atomic_store(hbF + (size_t)row * Hq + jbase + jh,
                                           hn, __ATOMIC_RELAXED,
                                           __HIP_MEMORY_SCOPE_AGENT);
                }
            }
        }

        // invalidate once per 8 phases: t = -1, 7, 15, ..., 255
        phasebar(sync, xcdgo, bid, slot, (unsigned)(t + 2),
                 (((t + 1) & 7) == 0));
    }

    // ---- final: out[b][o] = b_out[o] + sum_k hbF[b][k] * Wout[o][k] ----
    // (t=255 phasebar ran the inv -> hbF cached reads are fresh)
    int gid = bid * 512 + tid;
    if (gid < Bq * 128) {
        int b = gid >> 7, o = gid & 127;
        const floatx4* hr = (const floatx4*)(hbF + (size_t)b * Hq);
        const floatx4* wr = (const floatx4*)(Wout + (size_t)o * Hq);
        float s = bout[o];
#pragma unroll 4
        for (int k = 0; k < Hq / 4; ++k) {
            floatx4 hv = hr[k], wv = wr[k];
            s += hv[0] * wv[0] + hv[1] * wv[1] + hv[2] * wv[2] + hv[3] * wv[3];
        }
        out[gid] = s;
    }
}

// ---------------------------------------------------------------------------
extern "C" void kernel_launch(void* const* d_in, const int* in_sizes, int n_in,
                              void* d_out, int out_size, void* d_ws, size_t ws_size,
                              hipStream_t stream)
{
    (void)in_sizes; (void)n_in;
    float* out = (float*)d_out;

    if (ws_size < (size_t)REQ_WS) {
        float v = -(float)(ws_size >> 20);
        hipLaunchKernelGGL(ws_sentinel_kernel, dim3((out_size + 255) / 256), dim3(256),
                           0, stream, out, out_size, v);
        return;
    }

    const float* x    = (const float*)d_in[0];
    const float* h0   = (const float*)d_in[1];
    const float* c0   = (const float*)d_in[2];
    const float* Wih0 = (const float*)d_in[3];
    const float* Whh0 = (const float*)d_in[4];
    const float* bih0 = (const float*)d_in[5];
    const float* bhh0 = (const float*)d_in[6];
    const float* Wih1 = (const float*)d_in[7];
    const float* Whh1 = (const float*)d_in[8];
    const float* bih1 = (const float*)d_in[9];
    const float* bhh1 = (const float*)d_in[10];
    const float* Wout = (const float*)d_in[11];
    const float* bout = (const float*)d_in[12];

    char* ws = (char*)d_ws;
    _Float16* w1p  = (_Float16*)(ws + OFF_W1);
    _Float16* w0p  = (_Float16*)(ws + OFF_W0);
    _Float16* xh   = (_Float16*)(ws + OFF_XH);
    _Float16* bufA = (_Float16*)(ws + OFF_BA);
    _Float16* bufB = (_Float16*)(ws + OFF_BB);
    float*    hbF  = (float*)   (ws + OFF_HF);
    unsigned* sync = (unsigned*)(ws + OFF_SY);

    long long total = N_W1 + N_W0 + N_XH + N_H;   // 21,757,952 = 84992*256
    hipLaunchKernelGGL(prep_kernel, dim3((unsigned)(total / 256)), dim3(256), 0, stream,
                       x, h0, Wih0, Whh0, Wih1, Whh1, w1p, w0p, xh, bufA, bufB, sync);

    hipLaunchKernelGGL(lstm_main, dim3(256), dim3(512), 0, stream,
                       w1p, w0p, xh, bufA, bufB, hbF, c0,
                       bih0, bhh0, bih1, bhh1, Wout, bout, out, sync);
}

// Round 28
// 4808.192 us; speedup vs baseline: 1.1136x; 1.0079x over previous
//
#include <hip/hip_runtime.h>
#include <hip/hip_fp16.h>

// ---------------------------------------------------------------------------
// 2-layer LSTM (B=256, T=256, D=128, H=1024) + final Linear(H->128).
// Persistent kernel, one phase per timestep. fp16 MFMA, fp32 accum.
// Weights in LDS; h/x coalesced tiled layout (R22); ring-12 asm pipeline
// (R23); depth-8 h rotation + 1-in-8 invalidate (R25); HW transcendentals
// (R26).
//
// R28 = R26 (revert of R27's early-prologue, which violated the ring's
// vmcnt count contract + spilled async-pending asm registers -> GPU fault).
// ---------------------------------------------------------------------------

#define Bq 256
#define Hq 1024

typedef _Float16 half8 __attribute__((ext_vector_type(8)));
typedef float    floatx4 __attribute__((ext_vector_type(4)));

#define N_W1 8388608LL   // 128 cb * 65536  ([ks64][kb4][n2][jj16][e8])
#define N_W0 4718592LL   // 128 cb * 36864  ([ks36][kb4][n2][jj16][e8])
#define N_XH 8388608LL   // T*B*D  (tiled: [t][4][256][32])
#define N_H  262144LL    // B*H
#define BH   262144

// ws byte offsets (bufA/bufB: 8 rotating slots x 512 KB each)
#define OFF_W1 0LL
#define OFF_W0 16777216LL
#define OFF_XH 26214400LL
#define OFF_BA 42991616LL
#define OFF_BB 47185920LL
#define OFF_HF 51380224LL
#define OFF_SY 52428800LL
#define REQ_WS 52430848LL   // OFF_SY + 2048

// physical slot = bit-reverse-3 of logical slot (adjacent logicals >=2MB apart)
#define REV3(s) (((((s)) & 1) << 2) | ((s) & 2) | (((s) >> 2) & 1))

// ---------------------------------------------------------------------------
__global__ void ws_sentinel_kernel(float* __restrict__ out, int n, float v)
{
    int i = blockIdx.x * blockDim.x + threadIdx.x;
    if (i < n) out[i] = v;
}

// ---------------------------------------------------------------------------
__global__ void prep_kernel(const float* __restrict__ x, const float* __restrict__ h0,
                            const float* __restrict__ Wih0, const float* __restrict__ Whh0,
                            const float* __restrict__ Wih1, const float* __restrict__ Whh1,
                            _Float16* __restrict__ w1p, _Float16* __restrict__ w0p,
                            _Float16* __restrict__ xh,
                            _Float16* __restrict__ bufA, _Float16* __restrict__ bufB,
                            unsigned* __restrict__ sync)
{
    long long gid = (long long)blockIdx.x * blockDim.x + threadIdx.x;
    if (gid < 512) sync[gid] = 0u;   // [0..255]=arr flags, [256..]=xcdgo

    if (gid < N_W1) {
        // [cb][ks][kb][n][jj][e]; gate-col row = (2n + jj>>3)*1024 + cb*8 + (jj&7)
        long long i = gid;
        int e  = (int)(i & 7);
        int jj = (int)((i >> 3) & 15);
        int n  = (int)((i >> 7) & 1);
        int kb = (int)((i >> 8) & 3);
        int ks = (int)((i >> 10) & 63);
        int cb = (int)(i >> 16);
        int row = (2 * n + (jj >> 3)) * 1024 + cb * 8 + (jj & 7);
        int k = ks * 32 + kb * 8 + e;
        float v = (k < 1024) ? Wih1[(size_t)row * 1024 + k]
                             : Whh1[(size_t)row * 1024 + (k - 1024)];
        w1p[i] = (_Float16)v;
    } else if (gid < N_W1 + N_W0) {
        long long i = gid - N_W1;
        int cb = (int)(i / 36864LL);
        int r  = (int)(i - (long long)cb * 36864LL);
        int ks = r >> 10;
        int kb = (r >> 8) & 3;
        int n  = (r >> 7) & 1;
        int jj = (r >> 3) & 15;
        int e  = r & 7;
        int row = (2 * n + (jj >> 3)) * 1024 + cb * 8 + (jj & 7);
        int k = ks * 32 + kb * 8 + e;
        float v = (k < 128) ? Wih0[(size_t)row * 128 + k]
                            : Whh0[(size_t)row * 1024 + (k - 128)];
        w0p[i] = (_Float16)v;
    } else if (gid < N_W1 + N_W0 + N_XH) {
        long long i = gid - N_W1 - N_W0;
        // xh tiled: [t][tile4][b][32]; element d = tile*32+e of x[b][t][:]
        int t    = (int)(i >> 15);
        int rem  = (int)(i & 32767);
        int tile = rem >> 13;
        int b    = (rem >> 5) & 255;
        int e    = rem & 31;
        int d    = tile * 32 + e;
        xh[i] = (_Float16)x[((size_t)b * 256 + t) * 128 + d];
    } else if (gid < N_W1 + N_W0 + N_XH + N_H) {
        long long i = gid - N_W1 - N_W0 - N_XH;
        // h0 is [row][H]; tiled dest idx = (j>>5)*8192 + row*32 + (j&31)
        int row = (int)(i >> 10);
        int j   = (int)(i & 1023);
        size_t idx = (size_t)(j >> 5) * 8192 + (size_t)row * 32 + (j & 31);
        _Float16 v = (_Float16)h0[i];
        // h(-1) lives in logical slot 7 -> physical REV3(7)=7
        bufA[(size_t)7 * BH + idx] = v;
        bufB[(size_t)7 * BH + idx] = v;
    }
}

// ---------------------------------------------------------------------------
// Merged phase barrier (R23) with CONDITIONAL invalidate (R25).
__device__ __forceinline__ void phasebar(unsigned* flags, unsigned* xcdgo,
                                         int bid, int slot, unsigned target,
                                         int doinv)
{
    __builtin_amdgcn_s_waitcnt(0);     // own write-through stores at IF
    __syncthreads();
    if (threadIdx.x == 0)
        __hip_atomic_store(flags + bid, target, __ATOMIC_RELAXED,
                           __HIP_MEMORY_SCOPE_AGENT);
    if (slot == 0) {
        if (threadIdx.x < 256) {
            int guard = 0;
            while (__hip_atomic_load(flags + threadIdx.x, __ATOMIC_RELAXED,
                                     __HIP_MEMORY_SCOPE_AGENT) < target) {
                __builtin_amdgcn_s_sleep(1);
                if (++guard > (1 << 18)) break;    // safety: wrong, not wedged
            }
        }
        __syncthreads();
        if (threadIdx.x < 64) {
            if (doinv) {
                __builtin_amdgcn_fence(__ATOMIC_ACQUIRE, "agent");  // L2+L1 inv
                asm volatile("s_waitcnt vmcnt(0) lgkmcnt(0)" ::: "memory");
            }
            if (threadIdx.x == 0)
                __hip_atomic_store(xcdgo, target, __ATOMIC_RELAXED,
                                   __HIP_MEMORY_SCOPE_AGENT);
        }
        __syncthreads();
    } else {
        if (threadIdx.x == 0) {
            int guard = 0;
            while (__hip_atomic_load(xcdgo, __ATOMIC_RELAXED,
                                     __HIP_MEMORY_SCOPE_AGENT) < target) {
                __builtin_amdgcn_s_sleep(1);
                if (++guard > (1 << 18)) break;
            }
        }
        __syncthreads();
        if (doinv) {
            if (threadIdx.x == 0) {
                asm volatile("buffer_inv" ::: "memory");            // L1-only
                asm volatile("s_waitcnt vmcnt(0)" ::: "memory");
            }
            __syncthreads();
        }
    }
}

// ---- HW transcendentals ---------------------------------------------------
__device__ __forceinline__ float fexp2(float x)
{ float r; asm("v_exp_f32 %0, %1" : "=v"(r) : "v"(x)); return r; }
__device__ __forceinline__ float frcp(float x)
{ float r; asm("v_rcp_f32 %0, %1" : "=v"(r) : "v"(x)); return r; }
// sigmoid(x) = 1/(1+e^-x) = 1/(1+2^(-x*log2e))
__device__ __forceinline__ float fsig(float x)
{ return frcp(1.0f + fexp2(x * -1.44269504f)); }
// tanh(x) = 1 - 2/(e^(2x)+1) = 1 - 2/(2^(x*2*log2e)+1)
__device__ __forceinline__ float ftanhf_(float x)
{ return 1.0f - 2.0f * frcp(1.0f + fexp2(x * 2.88539008f)); }

#define MFMA16(A, Bv, C) __builtin_amdgcn_mfma_f32_16x16x32_f16((A), (Bv), (C), 0, 0, 0)

// ---- inline-asm ring-12 pipelined K-step machinery (R23) ------------------
#define PISSUE(I, P0, P1)                                           \
    asm volatile("global_load_dwordx4 %0, %2, off\n\t"              \
                 "global_load_dwordx4 %1, %3, off"                  \
                 : "=&v"(bf[I][0]), "=&v"(bf[I][1])                 \
                 : "v"(P0), "v"(P1) : "memory")

#define PSTEP22(I, P0, P1) do {                                     \
    half8 b0 = *(const half8*)(bp);                                 \
    half8 b1 = *(const half8*)(bp + 128);                           \
    asm volatile("s_waitcnt vmcnt(22)" ::: "memory");               \
    __builtin_amdgcn_sched_barrier(0);                              \
    acc[0][0] = MFMA16(bf[I][0], b0, acc[0][0]);                    \
    acc[0][1] = MFMA16(bf[I][0], b1, acc[0][1]);                    \
    acc[1][0] = MFMA16(bf[I][1], b0, acc[1][0]);                    \
    acc[1][1] = MFMA16(bf[I][1], b1, acc[1][1]);                    \
    bp += 1024;                                                     \
    PISSUE(I, P0, P1);                                              \
} while (0)

#define PSTEPW(I, NLIT) do {                                        \
    half8 b0 = *(const half8*)(bp);                                 \
    half8 b1 = *(const half8*)(bp + 128);                           \
    asm volatile("s_waitcnt vmcnt(" #NLIT ")" ::: "memory");        \
    __builtin_amdgcn_sched_barrier(0);                              \
    acc[0][0] = MFMA16(bf[I][0], b0, acc[0][0]);                    \
    acc[0][1] = MFMA16(bf[I][0], b1, acc[0][1]);                    \
    acc[1][0] = MFMA16(bf[I][1], b0, acc[1][0]);                    \
    acc[1][1] = MFMA16(bf[I][1], b1, acc[1][1]);                    \
    bp += 1024;                                                     \
} while (0)

__global__ void __launch_bounds__(512)
lstm_main(const _Float16* __restrict__ w1p, const _Float16* __restrict__ w0p,
          const _Float16* __restrict__ xh,
          _Float16* __restrict__ bufA, _Float16* __restrict__ bufB,
          float* __restrict__ hbF,
          const float* __restrict__ c0,
          const float* __restrict__ bih0, const float* __restrict__ bhh0,
          const float* __restrict__ bih1, const float* __restrict__ bhh1,
          const float* __restrict__ Wout, const float* __restrict__ bout,
          float* __restrict__ out, unsigned* __restrict__ sync)
{
    __shared__ _Float16 wlds[65536];   // 128 KiB

    const int tid  = threadIdx.x;
    const int lane = tid & 63;
    const int w    = tid >> 6;           // 0..7
    const int bid  = blockIdx.x;
    const int xcd  = bid & 7;
    const int slot = bid >> 3;           // 0..31
    const int isL1 = ((slot & 1) == 0);  // 16 L1 + 16 L0 blocks per XCD
    const int cb   = xcd * 16 + (slot >> 1);   // 0..127 column-block id
    const int jbase = cb * 8;
    const int jj = lane & 15;
    const int kb = lane >> 4;            // 0..3
    const int jh = jj & 7;
    const int lo = (jj < 8);
    const int rowbase = w * 32;          // wave's 32 batch rows

    unsigned* xcdgo = sync + 256 + xcd * 16;   // 64B-separated per-XCD flags

    // tiled h-store column index: j = jbase + jh -> tile cb>>2, col (cb&3)*8+jh
    const int jtile = cb >> 2;
    const int jcol  = (cb & 3) * 8 + jh;

    // ---- load this block's weights into LDS (once) ----
    {
        const _Float16* src = isL1 ? (w1p + (size_t)cb * 65536)
                                   : (w0p + (size_t)cb * 36864);
        const int nch = isL1 ? 8192 : 4608;   // 16B chunks
        for (int i = tid; i < nch; i += 512)
            *(half8*)&wlds[(size_t)i * 8] = *(const half8*)&src[(size_t)i * 8];
    }
    __syncthreads();

    // ---- biases + cell-state init ----
    const float* bi  = isL1 ? bih1 : bih0;
    const float* bhp = isL1 ? bhh1 : bhh0;
    float bias[4];
#pragma unroll
    for (int g = 0; g < 4; ++g)
        bias[g] = bi[g * 1024 + jbase + jh] + bhp[g * 1024 + jbase + jh];

    float cc[2][4];
#pragma unroll
    for (int mf = 0; mf < 2; ++mf)
#pragma unroll
        for (int r = 0; r < 4; ++r)
            cc[mf][r] = c0[(size_t)(rowbase + mf * 16 + kb * 4 + r) * Hq + jbase + jh];

    floatx4 acc[2][2];
    half8 bf[12][2];                     // ring: 12 slots x 2 frags = 96 VGPRs

    for (int t = -1; t <= 255; ++t) {
        const int active = isL1 ? (t >= 0) : (t < 255);
        if (active) {
#pragma unroll
            for (int mf = 0; mf < 2; ++mf)
#pragma unroll
                for (int n = 0; n < 2; ++n)
                    acc[mf][n] = (floatx4){0.f, 0.f, 0.f, 0.f};

            const _Float16* bp = wlds + kb * 256 + jj * 8;
            // per-lane tiled offset: (rowbase+jj)*32 + kb*8 -> 1KB/wave load
            const size_t loff = (size_t)(rowbase + jj) * 32 + kb * 8;

            // rotating h slots (physical = REV3(logical))
            const int sA = REV3(t & 7);          // h_a(t)
            const int sB = REV3((t + 7) & 7);    // h_b(t-1)

            if (isL1) {
                // gates1(t) = h_a(t)@Wih1^T + h_b(t-1)@Whh1^T  (64 K-steps)
                const _Float16* apA = bufA + (size_t)sA * BH + loff;
                const _Float16* apB = bufB + (size_t)sB * BH + loff;
#define L1P0(S) (((S) < 32) ? (apA + (size_t)(S) * 8192) : (apB + (size_t)((S) - 32) * 8192))
#define L1P1(S) (L1P0(S) + 512)
#pragma unroll
                for (int i = 0; i < 12; ++i) PISSUE(i, L1P0(i), L1P1(i));
#pragma unroll
                for (int s = 0; s < 52; ++s)
                    PSTEP22(s % 12, L1P0(s + 12), L1P1(s + 12));
                PSTEPW(4, 22);  PSTEPW(5, 20);  PSTEPW(6, 18);  PSTEPW(7, 16);
                PSTEPW(8, 14);  PSTEPW(9, 12);  PSTEPW(10, 10); PSTEPW(11, 8);
                PSTEPW(0, 6);   PSTEPW(1, 4);   PSTEPW(2, 2);   PSTEPW(3, 0);
#undef L1P0
#undef L1P1
            } else {
                // gates0(t+1) = x(t+1)@Wih0^T + h_a(t)@Whh0^T  (36 K-steps)
                const _Float16* apX = xh + (size_t)(t + 1) * 32768 + loff;
                const _Float16* apA = bufA + (size_t)sA * BH + loff;
#define L0P0(S) (((S) < 4) ? (apX + (size_t)(S) * 8192) : (apA + (size_t)((S) - 4) * 8192))
#define L0P1(S) (L0P0(S) + 512)
#pragma unroll
                for (int i = 0; i < 12; ++i) PISSUE(i, L0P0(i), L0P1(i));
#pragma unroll
                for (int s = 0; s < 24; ++s)
                    PSTEP22(s % 12, L0P0(s + 12), L0P1(s + 12));
                PSTEPW(0, 22);  PSTEPW(1, 20);  PSTEPW(2, 18);  PSTEPW(3, 16);
                PSTEPW(4, 14);  PSTEPW(5, 12);  PSTEPW(6, 10);  PSTEPW(7, 8);
                PSTEPW(8, 6);   PSTEPW(9, 4);   PSTEPW(10, 2);  PSTEPW(11, 0);
#undef L0P0
#undef L0P1
            }

            // ---- elementwise: gate-pair exchange + cell update + h store ----
            const int sW = isL1 ? REV3(t & 7) : REV3((t + 1) & 7);
            _Float16* hb = isL1 ? (bufB + (size_t)sW * BH)
                                : (bufA + (size_t)sW * BH);
            unsigned* hb32 = (unsigned*)hb;
#pragma unroll
            for (int mf = 0; mf < 2; ++mf) {
#pragma unroll
                for (int r = 0; r < 4; ++r) {
                    float o0 = acc[mf][0][r];       // lo: i, hi: f
                    float o1 = acc[mf][1][r];       // lo: g, hi: o
                    float p0 = __shfl_xor(o0, 8);
                    float p1 = __shfl_xor(o1, 8);
                    float gi = (lo ? o0 : p0) + bias[0];
                    float gf = (lo ? p0 : o0) + bias[1];
                    float gg = (lo ? o1 : p1) + bias[2];
                    float go = (lo ? p1 : o1) + bias[3];
                    float ii = fsig(gi);
                    float ff = fsig(gf);
                    float gt = ftanhf_(gg);
                    float oo = fsig(go);
                    float cn = ff * cc[mf][r] + ii * gt;
                    cc[mf][r] = cn;
                    float hn = oo * ftanhf_(cn);

                    union { _Float16 f; unsigned short u; } cv;
                    cv.f = (_Float16)hn;
                    int prt = __shfl_xor((int)cv.u, 1);   // neighbor j^1's bits
                    int row = rowbase + mf * 16 + kb * 4 + r;
                    if (lo && ((jh & 1) == 0)) {
                        unsigned word = (unsigned)cv.u | ((unsigned)prt << 16);
                        size_t eidx = (size_t)jtile * 8192 + (size_t)row * 32 + jcol;
                        __hip_atomic_store(hb32 + (eidx >> 1), word,
                                           __ATOMIC_RELAXED,
                                           __HIP_MEMORY_SCOPE_AGENT);
                    }
                    if (lo && isL1 && t == 255)
                        __hip_atomic_store(hbF + (size_t)row * Hq + jbase + jh,
                                           hn, __ATOMIC_RELAXED,
                                           __HIP_MEMORY_SCOPE_AGENT);
                }
            }
        }

        // invalidate once per 8 phases: t = -1, 7, 15, ..., 255
        phasebar(sync, xcdgo, bid, slot, (unsigned)(t + 2),
                 (((t + 1) & 7) == 0));
    }

    // ---- final: out[b][o] = b_out[o] + sum_k hbF[b][k] * Wout[o][k] ----
    // (t=255 phasebar ran the inv -> hbF cached reads are fresh)
    int gid = bid * 512 + tid;
    if (gid < Bq * 128) {
        int b = gid >> 7, o = gid & 127;
        const floatx4* hr = (const floatx4*)(hbF + (size_t)b * Hq);
        const floatx4* wr = (const floatx4*)(Wout + (size_t)o * Hq);
        float s = bout[o];
#pragma unroll 4
        for (int k = 0; k < Hq / 4; ++k) {
            floatx4 hv = hr[k], wv = wr[k];
            s += hv[0] * wv[0] + hv[1] * wv[1] + hv[2] * wv[2] + hv[3] * wv[3];
        }
        out[gid] = s;
    }
}

// ---------------------------------------------------------------------------
extern "C" void kernel_launch(void* const* d_in, const int* in_sizes, int n_in,
                              void* d_out, int out_size, void* d_ws, size_t ws_size,
                              hipStream_t stream)
{
    (void)in_sizes; (void)n_in;
    float* out = (float*)d_out;

    if (ws_size < (size_t)REQ_WS) {
        float v = -(float)(ws_size >> 20);
        hipLaunchKernelGGL(ws_sentinel_kernel, dim3((out_size + 255) / 256), dim3(256),
                           0, stream, out, out_size, v);
        return;
    }

    const float* x    = (const float*)d_in[0];
    const float* h0   = (const float*)d_in[1];
    const float* c0   = (const float*)d_in[2];
    const float* Wih0 = (const float*)d_in[3];
    const float* Whh0 = (const float*)d_in[4];
    const float* bih0 = (const float*)d_in[5];
    const float* bhh0 = (const float*)d_in[6];
    const float* Wih1 = (const float*)d_in[7];
    const float* Whh1 = (const float*)d_in[8];
    const float* bih1 = (const float*)d_in[9];
    const float* bhh1 = (const float*)d_in[10];
    const float* Wout = (const float*)d_in[11];
    const float* bout = (const float*)d_in[12];

    char* ws = (char*)d_ws;
    _Float16* w1p  = (_Float16*)(ws + OFF_W1);
    _Float16* w0p  = (_Float16*)(ws + OFF_W0);
    _Float16* xh   = (_Float16*)(ws + OFF_XH);
    _Float16* bufA = (_Float16*)(ws + OFF_BA);
    _Float16* bufB = (_Float16*)(ws + OFF_BB);
    float*    hbF  = (float*)   (ws + OFF_HF);
    unsigned* sync = (unsigned*)(ws + OFF_SY);

    long long total = N_W1 + N_W0 + N_XH + N_H;   // 21,757,952 = 84992*256
    hipLaunchKernelGGL(prep_kernel, dim3((unsigned)(total / 256)), dim3(256), 0, stream,
                       x, h0, Wih0, Whh0, Wih1, Whh1, w1p, w0p, xh, bufA, bufB, sync);

    hipLaunchKernelGGL(lstm_main, dim3(256), dim3(512), 0, stream,
                       w1p, w0p, xh, bufA, bufB, hbF, c0,
                       bih0, bhh0, bih1, bhh1, Wout, bout, out, sync);
}